// Round 6
// baseline (531.972 us; speedup 1.0000x reference)
//
#include <hip/hip_runtime.h>

#define B_ 8
#define NQ_ 2048
#define NK_ 2048
#define D_ 256
#define FSPLIT 4

typedef __attribute__((ext_vector_type(8))) short bf16x8_t;
typedef __attribute__((ext_vector_type(4))) float f32x4_t;

static __device__ __forceinline__ unsigned short f2bf(float x) {
  unsigned int u = __float_as_uint(x);
  unsigned int r = (u + 0x7FFFu + ((u >> 16) & 1u)) >> 16;
  return (unsigned short)r;
}
static __device__ __forceinline__ float bf2f(unsigned short b) {
  return __uint_as_float(((unsigned int)b) << 16);
}

// ---------------------------------------------------------------------------
// generic f32 -> split bf16 (hi + lo)
// ---------------------------------------------------------------------------
__global__ __launch_bounds__(256) void split_kernel(const float* __restrict__ x,
                                                    unsigned short* __restrict__ xh,
                                                    unsigned short* __restrict__ xl,
                                                    int n) {
  const int i = blockIdx.x * 256 + threadIdx.x;
  if (i < n) {
    const float v = x[i];
    const unsigned short hb = f2bf(v);
    xh[i] = hb;
    xl[i] = f2bf(v - bf2f(hb));
  }
}

// C[i][n] = cos(2*pi*(i*n mod 2048)/2048), i in [0,1152), split bf16
__global__ __launch_bounds__(256) void cos_split_kernel(unsigned short* __restrict__ Ch,
                                                        unsigned short* __restrict__ Cl) {
  const int idx = blockIdx.x * 256 + threadIdx.x;
  const int i = idx >> 11, n = idx & 2047;
  const int m = (i * n) & 2047;
  const float c = cosf((float)m * 0.0030679615757712823f);
  const unsigned short hb = f2bf(c);
  Ch[idx] = hb;
  Cl[idx] = f2bf(c - bf2f(hb));
}

// Qt[b][d][n] = split(query[b][n][d])
__global__ __launch_bounds__(256) void qt_split_kernel(const float* __restrict__ q,
                                                       unsigned short* __restrict__ Qth,
                                                       unsigned short* __restrict__ Qtl) {
  __shared__ float lds[32][33];
  const int t  = threadIdx.x;
  const int n0 = blockIdx.x * 32;
  const int d0 = blockIdx.y * 32;
  const int b  = blockIdx.z;
#pragma unroll
  for (int p = 0; p < 4; ++p) {
    const int idx = t + 256 * p;
    const int dd = idx & 31, nn = idx >> 5;
    lds[nn][dd] = q[((size_t)b * NQ_ + n0 + nn) * D_ + d0 + dd];
  }
  __syncthreads();
#pragma unroll
  for (int p = 0; p < 4; ++p) {
    const int idx = t + 256 * p;
    const int nn = idx & 31, dd = idx >> 5;
    const float v = lds[nn][dd];
    const unsigned short hb = f2bf(v);
    const size_t o = ((size_t)b * D_ + d0 + dd) * NQ_ + n0 + nn;
    Qth[o] = hb;
    Qtl[o] = f2bf(v - bf2f(hb));
  }
}

// Vt[b][d][j] = keyh[b][j][d]
__global__ __launch_bounds__(256) void vt_bf16_kernel(const unsigned short* __restrict__ keyh,
                                                      unsigned short* __restrict__ Vt) {
  __shared__ unsigned short lds[32][40];
  const int t  = threadIdx.x;
  const int j0 = blockIdx.x * 32;
  const int d0 = blockIdx.y * 32;
  const int b  = blockIdx.z;
#pragma unroll
  for (int p = 0; p < 4; ++p) {
    const int idx = t + 256 * p;
    const int dd = idx & 31, jj = idx >> 5;
    lds[jj][dd] = keyh[((size_t)b * NK_ + j0 + jj) * D_ + d0 + dd];
  }
  __syncthreads();
#pragma unroll
  for (int p = 0; p < 4; ++p) {
    const int idx = t + 256 * p;
    const int jj = idx & 31, dd = idx >> 5;
    Vt[((size_t)b * D_ + d0 + dd) * NK_ + j0 + jj] = lds[jj][dd];
  }
}

// ---------------------------------------------------------------------------
// DFT via split-bf16 3-MFMA, K-split=4 (atomicAdd f32 partials). (verified r4)
// ---------------------------------------------------------------------------
__global__ __launch_bounds__(256, 2) void dft_mfma(const unsigned short* __restrict__ Ch,
                                                   const unsigned short* __restrict__ Cl,
                                                   const unsigned short* __restrict__ Qth,
                                                   const unsigned short* __restrict__ Qtl,
                                                   float* __restrict__ qr) {
  __shared__ __align__(16) unsigned short Ah[128][72];
  __shared__ __align__(16) unsigned short Al[128][72];
  __shared__ __align__(16) unsigned short Bh[128][72];
  __shared__ __align__(16) unsigned short Bl[128][72];
  const int t = threadIdx.x;
  const int b = blockIdx.z >> 2, split = blockIdx.z & 3;
  const int i0 = blockIdx.x * 128, d0 = blockIdx.y * 128;
  const int w = t >> 6, lane = t & 63, quad = lane >> 4, l16 = lane & 15;
  const int wq = w & 1, wj = w >> 1;

  f32x4_t acc[4][4];
#pragma unroll
  for (int a = 0; a < 4; ++a)
#pragma unroll
    for (int c = 0; c < 4; ++c) acc[a][c] = (f32x4_t)0.f;

  const size_t abase = (size_t)i0 * 2048;
  const size_t bbase = ((size_t)b * D_ + d0) * 2048;

  for (int c0 = split * 512; c0 < split * 512 + 512; c0 += 64) {
#pragma unroll
    for (int it = 0; it < 4; ++it) {
      const int unit = t + 256 * it;
      const int row = unit >> 3, u = (unit & 7) * 8;
      const size_t go = (size_t)row * 2048 + c0 + u;
      *(uint4*)&Ah[row][u] = *(const uint4*)&Ch[abase + go];
      *(uint4*)&Al[row][u] = *(const uint4*)&Cl[abase + go];
      *(uint4*)&Bh[row][u] = *(const uint4*)&Qth[bbase + go];
      *(uint4*)&Bl[row][u] = *(const uint4*)&Qtl[bbase + go];
    }
    __syncthreads();
#pragma unroll
    for (int ks = 0; ks < 2; ++ks) {
      const int dcol = ks * 32 + quad * 8;
      bf16x8_t ah[4], al[4], bh[4], bl[4];
#pragma unroll
      for (int x = 0; x < 4; ++x) {
        ah[x] = *(const bf16x8_t*)&Ah[wq * 64 + x * 16 + l16][dcol];
        al[x] = *(const bf16x8_t*)&Al[wq * 64 + x * 16 + l16][dcol];
        bh[x] = *(const bf16x8_t*)&Bh[wj * 64 + x * 16 + l16][dcol];
        bl[x] = *(const bf16x8_t*)&Bl[wj * 64 + x * 16 + l16][dcol];
      }
#pragma unroll
      for (int at = 0; at < 4; ++at)
#pragma unroll
        for (int jt = 0; jt < 4; ++jt) {
          acc[at][jt] = __builtin_amdgcn_mfma_f32_16x16x32_bf16(ah[at], bh[jt], acc[at][jt], 0, 0, 0);
          acc[at][jt] = __builtin_amdgcn_mfma_f32_16x16x32_bf16(ah[at], bl[jt], acc[at][jt], 0, 0, 0);
          acc[at][jt] = __builtin_amdgcn_mfma_f32_16x16x32_bf16(al[at], bh[jt], acc[at][jt], 0, 0, 0);
        }
    }
    __syncthreads();
  }
#pragma unroll
  for (int at = 0; at < 4; ++at) {
#pragma unroll
    for (int jt = 0; jt < 4; ++jt) {
      const int d = d0 + wj * 64 + jt * 16 + l16;
#pragma unroll
      for (int r = 0; r < 4; ++r) {
        const int i = i0 + wq * 64 + at * 16 + quad * 4 + r;
        atomicAdd(&qr[((size_t)b * 1152 + i) * D_ + d], acc[at][jt][r]);
      }
    }
  }
}

// qrh/qrl[b][i][d] for all i: src = i<=1087 ? i : 2048-i
__global__ __launch_bounds__(256) void qr_finalize_kernel(const float* __restrict__ qr,
                                                          unsigned short* __restrict__ qrh,
                                                          unsigned short* __restrict__ qrl) {
  const int i = blockIdx.x, b = blockIdx.y, d = threadIdx.x;
  const int src = (i <= 1087) ? i : (2048 - i);
  const float v = qr[((size_t)b * 1152 + src) * D_ + d];
  const unsigned short hb = f2bf(v);
  const size_t o = ((size_t)b * NQ_ + i) * D_ + d;
  qrh[o] = hb;
  qrl[o] = f2bf(v - bf2f(hb));
}

// ---------------------------------------------------------------------------
// y = x @ W.T + bias -- split-bf16 3-MFMA, split epilogue (verified r3/r4)
// ---------------------------------------------------------------------------
__global__ __launch_bounds__(256, 2) void proj_mfma(const unsigned short* __restrict__ xh,
                                                    const unsigned short* __restrict__ xl,
                                                    const unsigned short* __restrict__ Wh,
                                                    const unsigned short* __restrict__ Wl,
                                                    const float* __restrict__ bias,
                                                    unsigned short* __restrict__ yh,
                                                    unsigned short* __restrict__ yl) {
  __shared__ __align__(16) unsigned short Xh[128][72];
  __shared__ __align__(16) unsigned short Xl[128][72];
  __shared__ __align__(16) unsigned short Bh[128][72];
  __shared__ __align__(16) unsigned short Bl[128][72];
  const int t = threadIdx.x;
  const int m0 = blockIdx.x * 128, o0 = blockIdx.y * 128;
  const int w = t >> 6, lane = t & 63, quad = lane >> 4, l16 = lane & 15;
  const int wq = w & 1, wj = w >> 1;

  f32x4_t acc[4][4];
#pragma unroll
  for (int a = 0; a < 4; ++a)
#pragma unroll
    for (int c = 0; c < 4; ++c) acc[a][c] = (f32x4_t)0.f;

  const size_t xbase = (size_t)m0 * D_;
  const size_t wbase = (size_t)o0 * D_;

  for (int c0 = 0; c0 < D_; c0 += 64) {
#pragma unroll
    for (int it = 0; it < 4; ++it) {
      const int unit = t + 256 * it;
      const int row = unit >> 3, u = (unit & 7) * 8;
      const size_t go = (size_t)row * D_ + c0 + u;
      *(uint4*)&Xh[row][u] = *(const uint4*)&xh[xbase + go];
      *(uint4*)&Xl[row][u] = *(const uint4*)&xl[xbase + go];
      *(uint4*)&Bh[row][u] = *(const uint4*)&Wh[wbase + go];
      *(uint4*)&Bl[row][u] = *(const uint4*)&Wl[wbase + go];
    }
    __syncthreads();
#pragma unroll
    for (int ks = 0; ks < 2; ++ks) {
      const int dcol = ks * 32 + quad * 8;
      bf16x8_t ah[4], al[4], bh[4], bl[4];
#pragma unroll
      for (int x = 0; x < 4; ++x) {
        ah[x] = *(const bf16x8_t*)&Xh[wq * 64 + x * 16 + l16][dcol];
        al[x] = *(const bf16x8_t*)&Xl[wq * 64 + x * 16 + l16][dcol];
        bh[x] = *(const bf16x8_t*)&Bh[wj * 64 + x * 16 + l16][dcol];
        bl[x] = *(const bf16x8_t*)&Bl[wj * 64 + x * 16 + l16][dcol];
      }
#pragma unroll
      for (int at = 0; at < 4; ++at)
#pragma unroll
        for (int jt = 0; jt < 4; ++jt) {
          acc[at][jt] = __builtin_amdgcn_mfma_f32_16x16x32_bf16(ah[at], bh[jt], acc[at][jt], 0, 0, 0);
          acc[at][jt] = __builtin_amdgcn_mfma_f32_16x16x32_bf16(ah[at], bl[jt], acc[at][jt], 0, 0, 0);
          acc[at][jt] = __builtin_amdgcn_mfma_f32_16x16x32_bf16(al[at], bh[jt], acc[at][jt], 0, 0, 0);
        }
    }
    __syncthreads();
  }
#pragma unroll
  for (int at = 0; at < 4; ++at) {
#pragma unroll
    for (int jt = 0; jt < 4; ++jt) {
      const int o = o0 + wj * 64 + jt * 16 + l16;
      const float bv = bias[o];
#pragma unroll
      for (int r = 0; r < 4; ++r) {
        const int m = m0 + wq * 64 + at * 16 + quad * 4 + r;
        const float v = acc[at][jt][r] + bv;
        const unsigned short hb = f2bf(v);
        yh[(size_t)m * D_ + o] = hb;
        yl[(size_t)m * D_ + o] = f2bf(v - bf2f(hb));
      }
    }
  }
}

// ---------------------------------------------------------------------------
// Fused flash attention, register-prefetched pipeline.
// Block: 64 Q-rows (16/wave, wave-private online softmax), j-range 512
// (FSPLIT=4), KV-tile 128. Global loads for stage k+1 issued during stage k's
// MFMA (uint4 regs), ds_write after the barrier -> latency hidden.
// Vs aliases the K buffers (phase-disjoint). P rows perm'd (r*4+quad) to
// spread b16-write banks.
// ---------------------------------------------------------------------------
__global__ __launch_bounds__(256, 2) void flash_mfma(const unsigned short* __restrict__ qh,
                                                     const unsigned short* __restrict__ ql,
                                                     const unsigned short* __restrict__ kh,
                                                     const unsigned short* __restrict__ kl,
                                                     const unsigned short* __restrict__ Vt,
                                                     float* __restrict__ Opart,
                                                     float2* __restrict__ mlpart) {
  __shared__ __align__(16) unsigned char smem[54272];
  unsigned short (*Khs)[72] = (unsigned short (*)[72])(smem);           // 18432
  unsigned short (*Kls)[72] = (unsigned short (*)[72])(smem + 18432);   // 18432
  unsigned short (*Vs)[136] = (unsigned short (*)[136])(smem);          // alias (17408)
  unsigned short (*Ps)[136] = (unsigned short (*)[136])(smem + 36864);  // 17408

  const int t = threadIdx.x;
  const int w = t >> 6, lane = t & 63, quad = lane >> 4, l16 = lane & 15;
  const int mb = blockIdx.x;
  const int b  = mb >> 5;
  const int m0 = mb * 64;
  const int split = blockIdx.y;
  const int jbase = split * (NK_ / FSPLIT);   // 512-wide j range

  f32x4_t o[16];
#pragma unroll
  for (int df = 0; df < 16; ++df) o[df] = (f32x4_t)0.f;
  float m_run[4], l_run[4];
#pragma unroll
  for (int r = 0; r < 4; ++r) { m_run[r] = -1e30f; l_run[r] = 0.f; }

  uint4 pkh[4], pkl[4], pvv[4];
  auto loadK = [&](int it8, int dc) {
#pragma unroll
    for (int it = 0; it < 4; ++it) {
      const int unit = t + 256 * it, row = unit >> 3, u = (unit & 7) * 8;
      const size_t go = ((size_t)b * NK_ + jbase + it8 * 128 + row) * D_ + dc * 64 + u;
      pkh[it] = *(const uint4*)&kh[go];
      pkl[it] = *(const uint4*)&kl[go];
    }
  };
  auto loadV = [&](int it8, int dc2) {
#pragma unroll
    for (int it = 0; it < 4; ++it) {
      const int unit = t + 256 * it, row = unit >> 4, u = (unit & 15) * 8;
      pvv[it] = *(const uint4*)&Vt[((size_t)b * D_ + dc2 * 64 + row) * NK_ + jbase + it8 * 128 + u];
    }
  };

  loadK(0, 0);
  for (int it8 = 0; it8 < NK_ / FSPLIT / 128; ++it8) {
    // --- phase A: S = scale * Q K^T (split-bf16 3-MFMA), 4 prefetched stages
    f32x4_t s[8];
#pragma unroll
    for (int jt = 0; jt < 8; ++jt) s[jt] = (f32x4_t)0.f;
#pragma unroll
    for (int dc = 0; dc < 4; ++dc) {
#pragma unroll
      for (int it = 0; it < 4; ++it) {
        const int unit = t + 256 * it, row = unit >> 3, u = (unit & 7) * 8;
        *(uint4*)&Khs[row][u] = pkh[it];
        *(uint4*)&Kls[row][u] = pkl[it];
      }
      __syncthreads();
      if (dc < 3) loadK(it8, dc + 1); else loadV(it8, 0);
#pragma unroll
      for (int ks = 0; ks < 2; ++ks) {
        const int ci = dc * 2 + ks;
        const size_t qoff = ((size_t)(m0 + w * 16 + l16)) * D_ + ci * 32 + quad * 8;
        const bf16x8_t qfh = *(const bf16x8_t*)&qh[qoff];
        const bf16x8_t qfl = *(const bf16x8_t*)&ql[qoff];
#pragma unroll
        for (int jt = 0; jt < 8; ++jt) {
          const bf16x8_t bh = *(const bf16x8_t*)&Khs[jt * 16 + l16][ks * 32 + quad * 8];
          const bf16x8_t bl = *(const bf16x8_t*)&Kls[jt * 16 + l16][ks * 32 + quad * 8];
          s[jt] = __builtin_amdgcn_mfma_f32_16x16x32_bf16(qfh, bh, s[jt], 0, 0, 0);
          s[jt] = __builtin_amdgcn_mfma_f32_16x16x32_bf16(qfh, bl, s[jt], 0, 0, 0);
          s[jt] = __builtin_amdgcn_mfma_f32_16x16x32_bf16(qfl, bh, s[jt], 0, 0, 0);
        }
      }
      __syncthreads();
    }

    // --- phase B: online softmax (wave-private rows; no barriers) ---
    float mt[4];
#pragma unroll
    for (int r = 0; r < 4; ++r) mt[r] = -1e30f;
#pragma unroll
    for (int jt = 0; jt < 8; ++jt)
#pragma unroll
      for (int r = 0; r < 4; ++r) {
        s[jt][r] *= 0.0625f;
        mt[r] = fmaxf(mt[r], s[jt][r]);
      }
#pragma unroll
    for (int off = 1; off < 16; off <<= 1)
#pragma unroll
      for (int r = 0; r < 4; ++r) mt[r] = fmaxf(mt[r], __shfl_xor(mt[r], off));
    float alr[4], ls[4];
#pragma unroll
    for (int r = 0; r < 4; ++r) {
      const float mn = fmaxf(m_run[r], mt[r]);
      alr[r] = __expf(m_run[r] - mn);
      m_run[r] = mn;
      ls[r] = 0.f;
    }
#pragma unroll
    for (int jt = 0; jt < 8; ++jt)
#pragma unroll
      for (int r = 0; r < 4; ++r) {
        const float p = __expf(s[jt][r] - m_run[r]);
        ls[r] += p;
        Ps[w * 16 + r * 4 + quad][jt * 16 + l16] = f2bf(p);  // perm'd row
      }
#pragma unroll
    for (int off = 1; off < 16; off <<= 1)
#pragma unroll
      for (int r = 0; r < 4; ++r) ls[r] += __shfl_xor(ls[r], off);
#pragma unroll
    for (int r = 0; r < 4; ++r) l_run[r] = l_run[r] * alr[r] + ls[r];
#pragma unroll
    for (int df = 0; df < 16; ++df)
#pragma unroll
      for (int r = 0; r < 4; ++r) o[df][r] *= alr[r];

    // --- phase C: O += P V, 4 prefetched stages (Vs aliases K bufs) ---
    const int pl = ((l16 & 3) << 2) | (l16 >> 2);   // inverse row perm
#pragma unroll
    for (int dc2 = 0; dc2 < 4; ++dc2) {
#pragma unroll
      for (int it = 0; it < 4; ++it) {
        const int unit = t + 256 * it, row = unit >> 4, u = (unit & 15) * 8;
        *(uint4*)&Vs[row][u] = pvv[it];
      }
      __syncthreads();
      if (dc2 < 3) loadV(it8, dc2 + 1);
      else if (it8 < NK_ / FSPLIT / 128 - 1) loadK(it8 + 1, 0);
#pragma unroll
      for (int kp = 0; kp < 4; ++kp) {
        const bf16x8_t a = *(const bf16x8_t*)&Ps[w * 16 + pl][kp * 32 + quad * 8];
#pragma unroll
        for (int df = 0; df < 4; ++df) {
          const bf16x8_t bv = *(const bf16x8_t*)&Vs[df * 16 + l16][kp * 32 + quad * 8];
          o[dc2 * 4 + df] =
              __builtin_amdgcn_mfma_f32_16x16x32_bf16(a, bv, o[dc2 * 4 + df], 0, 0, 0);
        }
      }
      __syncthreads();
    }
  }

  // --- epilogue: unnormalized O + (m, l) per row per split ---
  const size_t obase = ((size_t)split * (B_ * NQ_) + m0 + w * 16) * D_;
#pragma unroll
  for (int df = 0; df < 16; ++df)
#pragma unroll
    for (int r = 0; r < 4; ++r)
      Opart[obase + (size_t)(quad * 4 + r) * D_ + df * 16 + l16] = o[df][r];
  if (l16 == 0) {
#pragma unroll
    for (int r = 0; r < 4; ++r)
      mlpart[split * (B_ * NQ_) + m0 + w * 16 + quad * 4 + r] =
          make_float2(m_run[r], l_run[r]);
  }
}

// ---------------------------------------------------------------------------
// merge FSPLIT KV-splits + normalize
// ---------------------------------------------------------------------------
__global__ __launch_bounds__(256) void combine_kernel(const float* __restrict__ Opart,
                                                      const float2* __restrict__ mlpart,
                                                      float* __restrict__ out) {
  const int i = blockIdx.x;
  const int d = threadIdx.x;
  float2 st[FSPLIT];
  float M = -1e30f;
#pragma unroll
  for (int sp = 0; sp < FSPLIT; ++sp) {
    st[sp] = mlpart[sp * (B_ * NQ_) + i];
    M = fmaxf(M, st[sp].x);
  }
  float denom = 0.f, acc = 0.f;
#pragma unroll
  for (int sp = 0; sp < FSPLIT; ++sp) {
    const float e = __expf(st[sp].x - M);
    denom += e * st[sp].y;
    acc += e * Opart[((size_t)sp * (B_ * NQ_) + i) * D_ + d];
  }
  out[(size_t)i * D_ + d] = acc / denom;
}

extern "C" void kernel_launch(void* const* d_in, const int* in_sizes, int n_in,
                              void* d_out, int out_size, void* d_ws, size_t ws_size,
                              hipStream_t stream) {
  const float* query = (const float*)d_in[0];
  const float* key   = (const float*)d_in[1];
  const float* Wq    = (const float*)d_in[2];
  const float* bq    = (const float*)d_in[3];
  const float* Wk    = (const float*)d_in[4];
  const float* bk    = (const float*)d_in[5];
  float* out = (float*)d_out;

  char* ws = (char*)d_ws;
  const size_t MB = (size_t)1 << 20;
  // persistent:
  unsigned short* qh = (unsigned short*)(ws);            // 8 MB
  unsigned short* ql = (unsigned short*)(ws + 8 * MB);
  unsigned short* kh = (unsigned short*)(ws + 16 * MB);
  unsigned short* kl = (unsigned short*)(ws + 24 * MB);
  unsigned short* Vt = (unsigned short*)(ws + 32 * MB);
  float* Opart   = (float*)(ws + 40 * MB);               // 64 MB (4 splits x 16)
  float2* mlpart = (float2*)(ws + 104 * MB);             // 512 KB
  unsigned short* keyh = (unsigned short*)(ws + 105 * MB);  // 8 MB
  unsigned short* keyl = (unsigned short*)(ws + 113 * MB);  // 8 MB
  unsigned short* Wqh  = (unsigned short*)(ws + 121 * MB);  // 128 KB
  unsigned short* Wql  = (unsigned short*)(ws + 121 * MB + 256 * 1024);
  unsigned short* Wkh  = (unsigned short*)(ws + 121 * MB + 512 * 1024);
  unsigned short* Wkl  = (unsigned short*)(ws + 121 * MB + 768 * 1024);
  // transients overlaid on Opart (dead before flash_mfma writes Opart):
  unsigned short* Ch   = (unsigned short*)(ws + 40 * MB);   // 4.5 MB
  unsigned short* Cl   = (unsigned short*)(ws + 45 * MB);   // 4.5 MB
  unsigned short* Qth  = (unsigned short*)(ws + 50 * MB);   // 8 MB
  unsigned short* Qtl  = (unsigned short*)(ws + 58 * MB);   // 8 MB
  float*          qr   = (float*)(ws + 66 * MB);            // 9.44 MB
  unsigned short* qrh  = (unsigned short*)(ws + 76 * MB);   // 8 MB
  unsigned short* qrl  = (unsigned short*)(ws + 84 * MB);   // 8 MB -> ends 92 MB

  dim3 blk(256);
  hipMemsetAsync(qr, 0, (size_t)B_ * 1152 * D_ * sizeof(float), stream);

  split_kernel<<<B_ * NK_ * D_ / 256, blk, 0, stream>>>(key, keyh, keyl, B_ * NK_ * D_);
  split_kernel<<<D_ * D_ / 256, blk, 0, stream>>>(Wq, Wqh, Wql, D_ * D_);
  split_kernel<<<D_ * D_ / 256, blk, 0, stream>>>(Wk, Wkh, Wkl, D_ * D_);
  cos_split_kernel<<<1152 * 2048 / 256, blk, 0, stream>>>(Ch, Cl);
  qt_split_kernel<<<dim3(NQ_ / 32, D_ / 32, B_), blk, 0, stream>>>(query, Qth, Qtl);
  // DFT
  dft_mfma<<<dim3(9, 2, B_ * 4), blk, 0, stream>>>(Ch, Cl, Qth, Qtl, qr);
  qr_finalize_kernel<<<dim3(2048, B_), blk, 0, stream>>>(qr, qrh, qrl);
  // projections
  proj_mfma<<<dim3(B_ * NQ_ / 128, 2), blk, 0, stream>>>(qrh, qrl, Wqh, Wql, bq, qh, ql);
  proj_mfma<<<dim3(B_ * NK_ / 128, 2), blk, 0, stream>>>(keyh, keyl, Wkh, Wkl, bk, kh, kl);
  vt_bf16_kernel<<<dim3(NK_ / 32, D_ / 32, B_), blk, 0, stream>>>(keyh, Vt);
  // fused attention
  flash_mfma<<<dim3(B_ * NQ_ / 64, FSPLIT), blk, 0, stream>>>(qh, ql, kh, kl, Vt, Opart, mlpart);
  combine_kernel<<<B_ * NQ_, blk, 0, stream>>>(Opart, mlpart, out);
}

// Round 7
// 482.110 us; speedup vs baseline: 1.1034x; 1.1034x over previous
//
#include <hip/hip_runtime.h>

#define B_ 8
#define NQ_ 2048
#define NK_ 2048
#define D_ 256
#define FSPLIT 4

typedef __attribute__((ext_vector_type(8))) short bf16x8_t;
typedef __attribute__((ext_vector_type(4))) float f32x4_t;

static __device__ __forceinline__ unsigned short f2bf(float x) {
  unsigned int u = __float_as_uint(x);
  unsigned int r = (u + 0x7FFFu + ((u >> 16) & 1u)) >> 16;
  return (unsigned short)r;
}
static __device__ __forceinline__ float bf2f(unsigned short b) {
  return __uint_as_float(((unsigned int)b) << 16);
}

// ---------------------------------------------------------------------------
// generic f32 -> split bf16 (hi + lo)
// ---------------------------------------------------------------------------
__global__ __launch_bounds__(256) void split_kernel(const float* __restrict__ x,
                                                    unsigned short* __restrict__ xh,
                                                    unsigned short* __restrict__ xl,
                                                    int n) {
  const int i = blockIdx.x * 256 + threadIdx.x;
  if (i < n) {
    const float v = x[i];
    const unsigned short hb = f2bf(v);
    xh[i] = hb;
    xl[i] = f2bf(v - bf2f(hb));
  }
}

// C[i][n] = cos(2*pi*(i*n mod 2048)/2048), i in [0,1152), split bf16
__global__ __launch_bounds__(256) void cos_split_kernel(unsigned short* __restrict__ Ch,
                                                        unsigned short* __restrict__ Cl) {
  const int idx = blockIdx.x * 256 + threadIdx.x;
  const int i = idx >> 11, n = idx & 2047;
  const int m = (i * n) & 2047;
  const float c = cosf((float)m * 0.0030679615757712823f);
  const unsigned short hb = f2bf(c);
  Ch[idx] = hb;
  Cl[idx] = f2bf(c - bf2f(hb));
}

// Qt[b][d][n] = split(query[b][n][d])
__global__ __launch_bounds__(256) void qt_split_kernel(const float* __restrict__ q,
                                                       unsigned short* __restrict__ Qth,
                                                       unsigned short* __restrict__ Qtl) {
  __shared__ float lds[32][33];
  const int t  = threadIdx.x;
  const int n0 = blockIdx.x * 32;
  const int d0 = blockIdx.y * 32;
  const int b  = blockIdx.z;
#pragma unroll
  for (int p = 0; p < 4; ++p) {
    const int idx = t + 256 * p;
    const int dd = idx & 31, nn = idx >> 5;
    lds[nn][dd] = q[((size_t)b * NQ_ + n0 + nn) * D_ + d0 + dd];
  }
  __syncthreads();
#pragma unroll
  for (int p = 0; p < 4; ++p) {
    const int idx = t + 256 * p;
    const int nn = idx & 31, dd = idx >> 5;
    const float v = lds[nn][dd];
    const unsigned short hb = f2bf(v);
    const size_t o = ((size_t)b * D_ + d0 + dd) * NQ_ + n0 + nn;
    Qth[o] = hb;
    Qtl[o] = f2bf(v - bf2f(hb));
  }
}

// Vt[b][d][j] = keyh[b][j][d]
__global__ __launch_bounds__(256) void vt_bf16_kernel(const unsigned short* __restrict__ keyh,
                                                      unsigned short* __restrict__ Vt) {
  __shared__ unsigned short lds[32][40];
  const int t  = threadIdx.x;
  const int j0 = blockIdx.x * 32;
  const int d0 = blockIdx.y * 32;
  const int b  = blockIdx.z;
#pragma unroll
  for (int p = 0; p < 4; ++p) {
    const int idx = t + 256 * p;
    const int dd = idx & 31, jj = idx >> 5;
    lds[jj][dd] = keyh[((size_t)b * NK_ + j0 + jj) * D_ + d0 + dd];
  }
  __syncthreads();
#pragma unroll
  for (int p = 0; p < 4; ++p) {
    const int idx = t + 256 * p;
    const int jj = idx & 31, dd = idx >> 5;
    Vt[((size_t)b * D_ + d0 + dd) * NK_ + j0 + jj] = lds[jj][dd];
  }
}

// ---------------------------------------------------------------------------
// DFT via split-bf16 3-MFMA, K-split=4 (atomicAdd f32 partials). (verified r4)
// ---------------------------------------------------------------------------
__global__ __launch_bounds__(256, 2) void dft_mfma(const unsigned short* __restrict__ Ch,
                                                   const unsigned short* __restrict__ Cl,
                                                   const unsigned short* __restrict__ Qth,
                                                   const unsigned short* __restrict__ Qtl,
                                                   float* __restrict__ qr) {
  __shared__ __align__(16) unsigned short Ah[128][72];
  __shared__ __align__(16) unsigned short Al[128][72];
  __shared__ __align__(16) unsigned short Bh[128][72];
  __shared__ __align__(16) unsigned short Bl[128][72];
  const int t = threadIdx.x;
  const int b = blockIdx.z >> 2, split = blockIdx.z & 3;
  const int i0 = blockIdx.x * 128, d0 = blockIdx.y * 128;
  const int w = t >> 6, lane = t & 63, quad = lane >> 4, l16 = lane & 15;
  const int wq = w & 1, wj = w >> 1;

  f32x4_t acc[4][4];
#pragma unroll
  for (int a = 0; a < 4; ++a)
#pragma unroll
    for (int c = 0; c < 4; ++c) acc[a][c] = (f32x4_t)0.f;

  const size_t abase = (size_t)i0 * 2048;
  const size_t bbase = ((size_t)b * D_ + d0) * 2048;

  for (int c0 = split * 512; c0 < split * 512 + 512; c0 += 64) {
#pragma unroll
    for (int it = 0; it < 4; ++it) {
      const int unit = t + 256 * it;
      const int row = unit >> 3, u = (unit & 7) * 8;
      const size_t go = (size_t)row * 2048 + c0 + u;
      *(uint4*)&Ah[row][u] = *(const uint4*)&Ch[abase + go];
      *(uint4*)&Al[row][u] = *(const uint4*)&Cl[abase + go];
      *(uint4*)&Bh[row][u] = *(const uint4*)&Qth[bbase + go];
      *(uint4*)&Bl[row][u] = *(const uint4*)&Qtl[bbase + go];
    }
    __syncthreads();
#pragma unroll
    for (int ks = 0; ks < 2; ++ks) {
      const int dcol = ks * 32 + quad * 8;
      bf16x8_t ah[4], al[4], bh[4], bl[4];
#pragma unroll
      for (int x = 0; x < 4; ++x) {
        ah[x] = *(const bf16x8_t*)&Ah[wq * 64 + x * 16 + l16][dcol];
        al[x] = *(const bf16x8_t*)&Al[wq * 64 + x * 16 + l16][dcol];
        bh[x] = *(const bf16x8_t*)&Bh[wj * 64 + x * 16 + l16][dcol];
        bl[x] = *(const bf16x8_t*)&Bl[wj * 64 + x * 16 + l16][dcol];
      }
#pragma unroll
      for (int at = 0; at < 4; ++at)
#pragma unroll
        for (int jt = 0; jt < 4; ++jt) {
          acc[at][jt] = __builtin_amdgcn_mfma_f32_16x16x32_bf16(ah[at], bh[jt], acc[at][jt], 0, 0, 0);
          acc[at][jt] = __builtin_amdgcn_mfma_f32_16x16x32_bf16(ah[at], bl[jt], acc[at][jt], 0, 0, 0);
          acc[at][jt] = __builtin_amdgcn_mfma_f32_16x16x32_bf16(al[at], bh[jt], acc[at][jt], 0, 0, 0);
        }
    }
    __syncthreads();
  }
#pragma unroll
  for (int at = 0; at < 4; ++at) {
#pragma unroll
    for (int jt = 0; jt < 4; ++jt) {
      const int d = d0 + wj * 64 + jt * 16 + l16;
#pragma unroll
      for (int r = 0; r < 4; ++r) {
        const int i = i0 + wq * 64 + at * 16 + quad * 4 + r;
        atomicAdd(&qr[((size_t)b * 1152 + i) * D_ + d], acc[at][jt][r]);
      }
    }
  }
}

// qrh/qrl[b][i][d] for all i: src = i<=1087 ? i : 2048-i
__global__ __launch_bounds__(256) void qr_finalize_kernel(const float* __restrict__ qr,
                                                          unsigned short* __restrict__ qrh,
                                                          unsigned short* __restrict__ qrl) {
  const int i = blockIdx.x, b = blockIdx.y, d = threadIdx.x;
  const int src = (i <= 1087) ? i : (2048 - i);
  const float v = qr[((size_t)b * 1152 + src) * D_ + d];
  const unsigned short hb = f2bf(v);
  const size_t o = ((size_t)b * NQ_ + i) * D_ + d;
  qrh[o] = hb;
  qrl[o] = f2bf(v - bf2f(hb));
}

// ---------------------------------------------------------------------------
// y = x @ W.T + bias -- split-bf16 3-MFMA, split epilogue (verified r3/r4)
// ---------------------------------------------------------------------------
__global__ __launch_bounds__(256, 2) void proj_mfma(const unsigned short* __restrict__ xh,
                                                    const unsigned short* __restrict__ xl,
                                                    const unsigned short* __restrict__ Wh,
                                                    const unsigned short* __restrict__ Wl,
                                                    const float* __restrict__ bias,
                                                    unsigned short* __restrict__ yh,
                                                    unsigned short* __restrict__ yl) {
  __shared__ __align__(16) unsigned short Xh[128][72];
  __shared__ __align__(16) unsigned short Xl[128][72];
  __shared__ __align__(16) unsigned short Bh[128][72];
  __shared__ __align__(16) unsigned short Bl[128][72];
  const int t = threadIdx.x;
  const int m0 = blockIdx.x * 128, o0 = blockIdx.y * 128;
  const int w = t >> 6, lane = t & 63, quad = lane >> 4, l16 = lane & 15;
  const int wq = w & 1, wj = w >> 1;

  f32x4_t acc[4][4];
#pragma unroll
  for (int a = 0; a < 4; ++a)
#pragma unroll
    for (int c = 0; c < 4; ++c) acc[a][c] = (f32x4_t)0.f;

  const size_t xbase = (size_t)m0 * D_;
  const size_t wbase = (size_t)o0 * D_;

  for (int c0 = 0; c0 < D_; c0 += 64) {
#pragma unroll
    for (int it = 0; it < 4; ++it) {
      const int unit = t + 256 * it;
      const int row = unit >> 3, u = (unit & 7) * 8;
      const size_t go = (size_t)row * D_ + c0 + u;
      *(uint4*)&Xh[row][u] = *(const uint4*)&xh[xbase + go];
      *(uint4*)&Xl[row][u] = *(const uint4*)&xl[xbase + go];
      *(uint4*)&Bh[row][u] = *(const uint4*)&Wh[wbase + go];
      *(uint4*)&Bl[row][u] = *(const uint4*)&Wl[wbase + go];
    }
    __syncthreads();
#pragma unroll
    for (int ks = 0; ks < 2; ++ks) {
      const int dcol = ks * 32 + quad * 8;
      bf16x8_t ah[4], al[4], bh[4], bl[4];
#pragma unroll
      for (int x = 0; x < 4; ++x) {
        ah[x] = *(const bf16x8_t*)&Xh[wq * 64 + x * 16 + l16][dcol];
        al[x] = *(const bf16x8_t*)&Xl[wq * 64 + x * 16 + l16][dcol];
        bh[x] = *(const bf16x8_t*)&Bh[wj * 64 + x * 16 + l16][dcol];
        bl[x] = *(const bf16x8_t*)&Bl[wj * 64 + x * 16 + l16][dcol];
      }
#pragma unroll
      for (int at = 0; at < 4; ++at)
#pragma unroll
        for (int jt = 0; jt < 4; ++jt) {
          acc[at][jt] = __builtin_amdgcn_mfma_f32_16x16x32_bf16(ah[at], bh[jt], acc[at][jt], 0, 0, 0);
          acc[at][jt] = __builtin_amdgcn_mfma_f32_16x16x32_bf16(ah[at], bl[jt], acc[at][jt], 0, 0, 0);
          acc[at][jt] = __builtin_amdgcn_mfma_f32_16x16x32_bf16(al[at], bh[jt], acc[at][jt], 0, 0, 0);
        }
    }
    __syncthreads();
  }
#pragma unroll
  for (int at = 0; at < 4; ++at) {
#pragma unroll
    for (int jt = 0; jt < 4; ++jt) {
      const int o = o0 + wj * 64 + jt * 16 + l16;
      const float bv = bias[o];
#pragma unroll
      for (int r = 0; r < 4; ++r) {
        const int m = m0 + wq * 64 + at * 16 + quad * 4 + r;
        const float v = acc[at][jt][r] + bv;
        const unsigned short hb = f2bf(v);
        yh[(size_t)m * D_ + o] = hb;
        yl[(size_t)m * D_ + o] = f2bf(v - bf2f(hb));
      }
    }
  }
}

// ---------------------------------------------------------------------------
// Fused flash attention (r5 dataflow + K-prefetch only).
// Block: 64 Q-rows (16/wave, wave-private online softmax), j-range 512
// (FSPLIT=4), KV-tile 128. Q-fragments resident in regs (staged via LDS once).
// K chunk dc+1 is loaded into regs during chunk dc's MFMAs -> staging barrier
// no longer exposes global latency. V staged directly (latency covered by
// phase-B VALU and cross-block overlap). No V prefetch (VGPR budget).
// ---------------------------------------------------------------------------
__global__ __launch_bounds__(256, 2) void flash_mfma(const unsigned short* __restrict__ qh,
                                                     const unsigned short* __restrict__ ql,
                                                     const unsigned short* __restrict__ kh,
                                                     const unsigned short* __restrict__ kl,
                                                     const unsigned short* __restrict__ Vt,
                                                     float* __restrict__ Opart,
                                                     float2* __restrict__ mlpart) {
  __shared__ __align__(16) unsigned char smem[67584];
  unsigned short (*Khs)[72]  = (unsigned short (*)[72])(smem);           // 18432
  unsigned short (*Kls)[72]  = (unsigned short (*)[72])(smem + 18432);   // 18432
  unsigned short (*Ps)[136]  = (unsigned short (*)[136])(smem + 36864);  // 17408
  unsigned short (*Vs)[136]  = (unsigned short (*)[136])(smem);          // alias (17408)
  unsigned short (*Qhs)[264] = (unsigned short (*)[264])(smem);          // startup only
  unsigned short (*Qls)[264] = (unsigned short (*)[264])(smem + 33792);  // startup only

  const int t = threadIdx.x;
  const int w = t >> 6, lane = t & 63, quad = lane >> 4, l16 = lane & 15;
  const int mb = blockIdx.x;
  const int b  = mb >> 5;
  const int m0 = mb * 64;
  const int split = blockIdx.y;
  const int jbase = split * (NK_ / FSPLIT);   // 512-wide j range

  // --- stage Q tile (64 x 256, hi+lo) via LDS, pull fragments to registers ---
  {
    const size_t qbase = (size_t)m0 * D_;
#pragma unroll
    for (int it = 0; it < 8; ++it) {
      const int unit = t + 256 * it;
      const int row = unit >> 5, u = (unit & 31) * 8;
      *(uint4*)&Qhs[row][u] = *(const uint4*)&qh[qbase + (size_t)row * D_ + u];
      *(uint4*)&Qls[row][u] = *(const uint4*)&ql[qbase + (size_t)row * D_ + u];
    }
  }
  __syncthreads();
  bf16x8_t qf_h[8], qf_l[8];
#pragma unroll
  for (int c = 0; c < 8; ++c) {
    qf_h[c] = *(const bf16x8_t*)&Qhs[w * 16 + l16][c * 32 + quad * 8];
    qf_l[c] = *(const bf16x8_t*)&Qls[w * 16 + l16][c * 32 + quad * 8];
  }
  __syncthreads();   // Q region reused for K/V below

  f32x4_t o[16];
#pragma unroll
  for (int df = 0; df < 16; ++df) o[df] = (f32x4_t)0.f;
  float m_run[4], l_run[4];
#pragma unroll
  for (int r = 0; r < 4; ++r) { m_run[r] = -1e30f; l_run[r] = 0.f; }

  uint4 pkh[4], pkl[4];
  auto loadK = [&](int it8, int dc) {
#pragma unroll
    for (int it = 0; it < 4; ++it) {
      const int unit = t + 256 * it, row = unit >> 3, u = (unit & 7) * 8;
      const size_t go = ((size_t)b * NK_ + jbase + it8 * 128 + row) * D_ + dc * 64 + u;
      pkh[it] = *(const uint4*)&kh[go];
      pkl[it] = *(const uint4*)&kl[go];
    }
  };

  loadK(0, 0);
  for (int it8 = 0; it8 < NK_ / FSPLIT / 128; ++it8) {
    // --- phase A: S = scale * Q K^T (split-bf16 3-MFMA), K-prefetched ---
    f32x4_t s[8];
#pragma unroll
    for (int jt = 0; jt < 8; ++jt) s[jt] = (f32x4_t)0.f;
#pragma unroll
    for (int dc = 0; dc < 4; ++dc) {
#pragma unroll
      for (int it = 0; it < 4; ++it) {
        const int unit = t + 256 * it, row = unit >> 3, u = (unit & 7) * 8;
        *(uint4*)&Khs[row][u] = pkh[it];
        *(uint4*)&Kls[row][u] = pkl[it];
      }
      __syncthreads();
      if (dc < 3) loadK(it8, dc + 1);
#pragma unroll
      for (int ks = 0; ks < 2; ++ks) {
        const int ci = dc * 2 + ks;
#pragma unroll
        for (int jt = 0; jt < 8; ++jt) {
          const bf16x8_t bh = *(const bf16x8_t*)&Khs[jt * 16 + l16][ks * 32 + quad * 8];
          const bf16x8_t bl = *(const bf16x8_t*)&Kls[jt * 16 + l16][ks * 32 + quad * 8];
          s[jt] = __builtin_amdgcn_mfma_f32_16x16x32_bf16(qf_h[ci], bh, s[jt], 0, 0, 0);
          s[jt] = __builtin_amdgcn_mfma_f32_16x16x32_bf16(qf_h[ci], bl, s[jt], 0, 0, 0);
          s[jt] = __builtin_amdgcn_mfma_f32_16x16x32_bf16(qf_l[ci], bh, s[jt], 0, 0, 0);
        }
      }
      __syncthreads();
    }

    // --- phase B: online softmax (wave-private rows; no barriers) ---
    float mt[4];
#pragma unroll
    for (int r = 0; r < 4; ++r) mt[r] = -1e30f;
#pragma unroll
    for (int jt = 0; jt < 8; ++jt)
#pragma unroll
      for (int r = 0; r < 4; ++r) {
        s[jt][r] *= 0.0625f;
        mt[r] = fmaxf(mt[r], s[jt][r]);
      }
#pragma unroll
    for (int off = 1; off < 16; off <<= 1)
#pragma unroll
      for (int r = 0; r < 4; ++r) mt[r] = fmaxf(mt[r], __shfl_xor(mt[r], off));
    float alr[4], ls[4];
#pragma unroll
    for (int r = 0; r < 4; ++r) {
      const float mn = fmaxf(m_run[r], mt[r]);
      alr[r] = __expf(m_run[r] - mn);
      m_run[r] = mn;
      ls[r] = 0.f;
    }
#pragma unroll
    for (int jt = 0; jt < 8; ++jt)
#pragma unroll
      for (int r = 0; r < 4; ++r) {
        const float p = __expf(s[jt][r] - m_run[r]);
        ls[r] += p;
        Ps[w * 16 + quad * 4 + r][jt * 16 + l16] = f2bf(p);
      }
#pragma unroll
    for (int off = 1; off < 16; off <<= 1)
#pragma unroll
      for (int r = 0; r < 4; ++r) ls[r] += __shfl_xor(ls[r], off);
#pragma unroll
    for (int r = 0; r < 4; ++r) l_run[r] = l_run[r] * alr[r] + ls[r];
#pragma unroll
    for (int df = 0; df < 16; ++df)
#pragma unroll
      for (int r = 0; r < 4; ++r) o[df][r] *= alr[r];

    // --- phase C: O += P V (Vs aliases K bufs; K for next it8 prefetched) ---
#pragma unroll
    for (int dc2 = 0; dc2 < 4; ++dc2) {
#pragma unroll
      for (int it = 0; it < 4; ++it) {
        const int unit = t + 256 * it, row = unit >> 4, u = (unit & 15) * 8;
        *(uint4*)&Vs[row][u] =
            *(const uint4*)&Vt[((size_t)b * D_ + dc2 * 64 + row) * NK_ + jbase + it8 * 128 + u];
      }
      __syncthreads();
      if (dc2 == 3 && it8 < NK_ / FSPLIT / 128 - 1) loadK(it8 + 1, 0);
#pragma unroll
      for (int kp = 0; kp < 4; ++kp) {
        const bf16x8_t a = *(const bf16x8_t*)&Ps[w * 16 + l16][kp * 32 + quad * 8];
#pragma unroll
        for (int df = 0; df < 4; ++df) {
          const bf16x8_t bv = *(const bf16x8_t*)&Vs[df * 16 + l16][kp * 32 + quad * 8];
          o[dc2 * 4 + df] =
              __builtin_amdgcn_mfma_f32_16x16x32_bf16(a, bv, o[dc2 * 4 + df], 0, 0, 0);
        }
      }
      __syncthreads();
    }
  }

  // --- epilogue: unnormalized O + (m, l) per row per split ---
  const size_t obase = ((size_t)split * (B_ * NQ_) + m0 + w * 16) * D_;
#pragma unroll
  for (int df = 0; df < 16; ++df)
#pragma unroll
    for (int r = 0; r < 4; ++r)
      Opart[obase + (size_t)(quad * 4 + r) * D_ + df * 16 + l16] = o[df][r];
  if (l16 == 0) {
#pragma unroll
    for (int r = 0; r < 4; ++r)
      mlpart[split * (B_ * NQ_) + m0 + w * 16 + quad * 4 + r] =
          make_float2(m_run[r], l_run[r]);
  }
}

// ---------------------------------------------------------------------------
// merge FSPLIT KV-splits + normalize
// ---------------------------------------------------------------------------
__global__ __launch_bounds__(256) void combine_kernel(const float* __restrict__ Opart,
                                                      const float2* __restrict__ mlpart,
                                                      float* __restrict__ out) {
  const int i = blockIdx.x;
  const int d = threadIdx.x;
  float2 st[FSPLIT];
  float M = -1e30f;
#pragma unroll
  for (int sp = 0; sp < FSPLIT; ++sp) {
    st[sp] = mlpart[sp * (B_ * NQ_) + i];
    M = fmaxf(M, st[sp].x);
  }
  float denom = 0.f, acc = 0.f;
#pragma unroll
  for (int sp = 0; sp < FSPLIT; ++sp) {
    const float e = __expf(st[sp].x - M);
    denom += e * st[sp].y;
    acc += e * Opart[((size_t)sp * (B_ * NQ_) + i) * D_ + d];
  }
  out[(size_t)i * D_ + d] = acc / denom;
}

extern "C" void kernel_launch(void* const* d_in, const int* in_sizes, int n_in,
                              void* d_out, int out_size, void* d_ws, size_t ws_size,
                              hipStream_t stream) {
  const float* query = (const float*)d_in[0];
  const float* key   = (const float*)d_in[1];
  const float* Wq    = (const float*)d_in[2];
  const float* bq    = (const float*)d_in[3];
  const float* Wk    = (const float*)d_in[4];
  const float* bk    = (const float*)d_in[5];
  float* out = (float*)d_out;

  char* ws = (char*)d_ws;
  const size_t MB = (size_t)1 << 20;
  // persistent:
  unsigned short* qh = (unsigned short*)(ws);            // 8 MB
  unsigned short* ql = (unsigned short*)(ws + 8 * MB);
  unsigned short* kh = (unsigned short*)(ws + 16 * MB);
  unsigned short* kl = (unsigned short*)(ws + 24 * MB);
  unsigned short* Vt = (unsigned short*)(ws + 32 * MB);
  float* Opart   = (float*)(ws + 40 * MB);               // 64 MB (4 splits)
  float2* mlpart = (float2*)(ws + 104 * MB);             // 512 KB
  unsigned short* keyh = (unsigned short*)(ws + 105 * MB);  // 8 MB
  unsigned short* keyl = (unsigned short*)(ws + 113 * MB);  // 8 MB
  unsigned short* Wqh  = (unsigned short*)(ws + 121 * MB);  // 128 KB
  unsigned short* Wql  = (unsigned short*)(ws + 121 * MB + 256 * 1024);
  unsigned short* Wkh  = (unsigned short*)(ws + 121 * MB + 512 * 1024);
  unsigned short* Wkl  = (unsigned short*)(ws + 121 * MB + 768 * 1024);
  // transients overlaid on Opart (dead before flash_mfma writes Opart):
  unsigned short* Ch   = (unsigned short*)(ws + 40 * MB);   // 4.5 MB
  unsigned short* Cl   = (unsigned short*)(ws + 45 * MB);   // 4.5 MB
  unsigned short* Qth  = (unsigned short*)(ws + 50 * MB);   // 8 MB
  unsigned short* Qtl  = (unsigned short*)(ws + 58 * MB);   // 8 MB
  float*          qr   = (float*)(ws + 66 * MB);            // 9.44 MB
  unsigned short* qrh  = (unsigned short*)(ws + 76 * MB);   // 8 MB
  unsigned short* qrl  = (unsigned short*)(ws + 84 * MB);   // 8 MB -> ends 92 MB

  dim3 blk(256);
  hipMemsetAsync(qr, 0, (size_t)B_ * 1152 * D_ * sizeof(float), stream);

  split_kernel<<<B_ * NK_ * D_ / 256, blk, 0, stream>>>(key, keyh, keyl, B_ * NK_ * D_);
  split_kernel<<<D_ * D_ / 256, blk, 0, stream>>>(Wq, Wqh, Wql, D_ * D_);
  split_kernel<<<D_ * D_ / 256, blk, 0, stream>>>(Wk, Wkh, Wkl, D_ * D_);
  cos_split_kernel<<<1152 * 2048 / 256, blk, 0, stream>>>(Ch, Cl);
  qt_split_kernel<<<dim3(NQ_ / 32, D_ / 32, B_), blk, 0, stream>>>(query, Qth, Qtl);
  // DFT
  dft_mfma<<<dim3(9, 2, B_ * 4), blk, 0, stream>>>(Ch, Cl, Qth, Qtl, qr);
  qr_finalize_kernel<<<dim3(2048, B_), blk, 0, stream>>>(qr, qrh, qrl);
  // projections
  proj_mfma<<<dim3(B_ * NQ_ / 128, 2), blk, 0, stream>>>(qrh, qrl, Wqh, Wql, bq, qh, ql);
  proj_mfma<<<dim3(B_ * NK_ / 128, 2), blk, 0, stream>>>(keyh, keyl, Wkh, Wkl, bk, kh, kl);
  vt_bf16_kernel<<<dim3(NK_ / 32, D_ / 32, B_), blk, 0, stream>>>(keyh, Vt);
  // fused attention
  flash_mfma<<<dim3(B_ * NQ_ / 64, FSPLIT), blk, 0, stream>>>(qh, ql, kh, kl, Vt, Opart, mlpart);
  combine_kernel<<<B_ * NQ_, blk, 0, stream>>>(Opart, mlpart, out);
}

// Round 8
// 377.898 us; speedup vs baseline: 1.4077x; 1.2758x over previous
//
#include <hip/hip_runtime.h>

#define B_ 8
#define NQ_ 2048
#define NK_ 2048
#define D_ 256

typedef __attribute__((ext_vector_type(8))) short bf16x8_t;
typedef __attribute__((ext_vector_type(4))) float f32x4_t;

static __device__ __forceinline__ unsigned short f2bf(float x) {
  unsigned int u = __float_as_uint(x);
  unsigned int r = (u + 0x7FFFu + ((u >> 16) & 1u)) >> 16;
  return (unsigned short)r;
}
static __device__ __forceinline__ float bf2f(unsigned short b) {
  return __uint_as_float(((unsigned int)b) << 16);
}

// ---------------------------------------------------------------------------
// generic f32 -> split bf16 (hi + lo)
// ---------------------------------------------------------------------------
__global__ __launch_bounds__(256) void split_kernel(const float* __restrict__ x,
                                                    unsigned short* __restrict__ xh,
                                                    unsigned short* __restrict__ xl,
                                                    int n) {
  const int i = blockIdx.x * 256 + threadIdx.x;
  if (i < n) {
    const float v = x[i];
    const unsigned short hb = f2bf(v);
    xh[i] = hb;
    xl[i] = f2bf(v - bf2f(hb));
  }
}

// C[i][n] = cos(2*pi*(i*n mod 2048)/2048), i in [0,1152), split bf16
__global__ __launch_bounds__(256) void cos_split_kernel(unsigned short* __restrict__ Ch,
                                                        unsigned short* __restrict__ Cl) {
  const int idx = blockIdx.x * 256 + threadIdx.x;
  const int i = idx >> 11, n = idx & 2047;
  const int m = (i * n) & 2047;
  const float c = cosf((float)m * 0.0030679615757712823f);
  const unsigned short hb = f2bf(c);
  Ch[idx] = hb;
  Cl[idx] = f2bf(c - bf2f(hb));
}

// Qt[b][d][n] = split(query[b][n][d])
__global__ __launch_bounds__(256) void qt_split_kernel(const float* __restrict__ q,
                                                       unsigned short* __restrict__ Qth,
                                                       unsigned short* __restrict__ Qtl) {
  __shared__ float lds[32][33];
  const int t  = threadIdx.x;
  const int n0 = blockIdx.x * 32;
  const int d0 = blockIdx.y * 32;
  const int b  = blockIdx.z;
#pragma unroll
  for (int p = 0; p < 4; ++p) {
    const int idx = t + 256 * p;
    const int dd = idx & 31, nn = idx >> 5;
    lds[nn][dd] = q[((size_t)b * NQ_ + n0 + nn) * D_ + d0 + dd];
  }
  __syncthreads();
#pragma unroll
  for (int p = 0; p < 4; ++p) {
    const int idx = t + 256 * p;
    const int nn = idx & 31, dd = idx >> 5;
    const float v = lds[nn][dd];
    const unsigned short hb = f2bf(v);
    const size_t o = ((size_t)b * D_ + d0 + dd) * NQ_ + n0 + nn;
    Qth[o] = hb;
    Qtl[o] = f2bf(v - bf2f(hb));
  }
}

// Vt[b][d][j] = keyh[b][j][d]
__global__ __launch_bounds__(256) void vt_bf16_kernel(const unsigned short* __restrict__ keyh,
                                                      unsigned short* __restrict__ Vt) {
  __shared__ unsigned short lds[32][40];
  const int t  = threadIdx.x;
  const int j0 = blockIdx.x * 32;
  const int d0 = blockIdx.y * 32;
  const int b  = blockIdx.z;
#pragma unroll
  for (int p = 0; p < 4; ++p) {
    const int idx = t + 256 * p;
    const int dd = idx & 31, jj = idx >> 5;
    lds[jj][dd] = keyh[((size_t)b * NK_ + j0 + jj) * D_ + d0 + dd];
  }
  __syncthreads();
#pragma unroll
  for (int p = 0; p < 4; ++p) {
    const int idx = t + 256 * p;
    const int jj = idx & 31, dd = idx >> 5;
    Vt[((size_t)b * D_ + d0 + dd) * NK_ + j0 + jj] = lds[jj][dd];
  }
}

// ---------------------------------------------------------------------------
// DFT via split-bf16 3-MFMA, K-split=4 (atomicAdd f32 partials). (verified r4)
// ---------------------------------------------------------------------------
__global__ __launch_bounds__(256, 2) void dft_mfma(const unsigned short* __restrict__ Ch,
                                                   const unsigned short* __restrict__ Cl,
                                                   const unsigned short* __restrict__ Qth,
                                                   const unsigned short* __restrict__ Qtl,
                                                   float* __restrict__ qr) {
  __shared__ __align__(16) unsigned short Ah[128][72];
  __shared__ __align__(16) unsigned short Al[128][72];
  __shared__ __align__(16) unsigned short Bh[128][72];
  __shared__ __align__(16) unsigned short Bl[128][72];
  const int t = threadIdx.x;
  const int b = blockIdx.z >> 2, split = blockIdx.z & 3;
  const int i0 = blockIdx.x * 128, d0 = blockIdx.y * 128;
  const int w = t >> 6, lane = t & 63, quad = lane >> 4, l16 = lane & 15;
  const int wq = w & 1, wj = w >> 1;

  f32x4_t acc[4][4];
#pragma unroll
  for (int a = 0; a < 4; ++a)
#pragma unroll
    for (int c = 0; c < 4; ++c) acc[a][c] = (f32x4_t)0.f;

  const size_t abase = (size_t)i0 * 2048;
  const size_t bbase = ((size_t)b * D_ + d0) * 2048;

  for (int c0 = split * 512; c0 < split * 512 + 512; c0 += 64) {
#pragma unroll
    for (int it = 0; it < 4; ++it) {
      const int unit = t + 256 * it;
      const int row = unit >> 3, u = (unit & 7) * 8;
      const size_t go = (size_t)row * 2048 + c0 + u;
      *(uint4*)&Ah[row][u] = *(const uint4*)&Ch[abase + go];
      *(uint4*)&Al[row][u] = *(const uint4*)&Cl[abase + go];
      *(uint4*)&Bh[row][u] = *(const uint4*)&Qth[bbase + go];
      *(uint4*)&Bl[row][u] = *(const uint4*)&Qtl[bbase + go];
    }
    __syncthreads();
#pragma unroll
    for (int ks = 0; ks < 2; ++ks) {
      const int dcol = ks * 32 + quad * 8;
      bf16x8_t ah[4], al[4], bh[4], bl[4];
#pragma unroll
      for (int x = 0; x < 4; ++x) {
        ah[x] = *(const bf16x8_t*)&Ah[wq * 64 + x * 16 + l16][dcol];
        al[x] = *(const bf16x8_t*)&Al[wq * 64 + x * 16 + l16][dcol];
        bh[x] = *(const bf16x8_t*)&Bh[wj * 64 + x * 16 + l16][dcol];
        bl[x] = *(const bf16x8_t*)&Bl[wj * 64 + x * 16 + l16][dcol];
      }
#pragma unroll
      for (int at = 0; at < 4; ++at)
#pragma unroll
        for (int jt = 0; jt < 4; ++jt) {
          acc[at][jt] = __builtin_amdgcn_mfma_f32_16x16x32_bf16(ah[at], bh[jt], acc[at][jt], 0, 0, 0);
          acc[at][jt] = __builtin_amdgcn_mfma_f32_16x16x32_bf16(ah[at], bl[jt], acc[at][jt], 0, 0, 0);
          acc[at][jt] = __builtin_amdgcn_mfma_f32_16x16x32_bf16(al[at], bh[jt], acc[at][jt], 0, 0, 0);
        }
    }
    __syncthreads();
  }
#pragma unroll
  for (int at = 0; at < 4; ++at) {
#pragma unroll
    for (int jt = 0; jt < 4; ++jt) {
      const int d = d0 + wj * 64 + jt * 16 + l16;
#pragma unroll
      for (int r = 0; r < 4; ++r) {
        const int i = i0 + wq * 64 + at * 16 + quad * 4 + r;
        atomicAdd(&qr[((size_t)b * 1152 + i) * D_ + d], acc[at][jt][r]);
      }
    }
  }
}

// qrh/qrl[b][i][d] for all i: src = i<=1087 ? i : 2048-i
__global__ __launch_bounds__(256) void qr_finalize_kernel(const float* __restrict__ qr,
                                                          unsigned short* __restrict__ qrh,
                                                          unsigned short* __restrict__ qrl) {
  const int i = blockIdx.x, b = blockIdx.y, d = threadIdx.x;
  const int src = (i <= 1087) ? i : (2048 - i);
  const float v = qr[((size_t)b * 1152 + src) * D_ + d];
  const unsigned short hb = f2bf(v);
  const size_t o = ((size_t)b * NQ_ + i) * D_ + d;
  qrh[o] = hb;
  qrl[o] = f2bf(v - bf2f(hb));
}

// ---------------------------------------------------------------------------
// y = x @ W.T + bias -- split-bf16 3-MFMA, split epilogue (verified r3/r4)
// ---------------------------------------------------------------------------
__global__ __launch_bounds__(256, 2) void proj_mfma(const unsigned short* __restrict__ xh,
                                                    const unsigned short* __restrict__ xl,
                                                    const unsigned short* __restrict__ Wh,
                                                    const unsigned short* __restrict__ Wl,
                                                    const float* __restrict__ bias,
                                                    unsigned short* __restrict__ yh,
                                                    unsigned short* __restrict__ yl) {
  __shared__ __align__(16) unsigned short Xh[128][72];
  __shared__ __align__(16) unsigned short Xl[128][72];
  __shared__ __align__(16) unsigned short Bh[128][72];
  __shared__ __align__(16) unsigned short Bl[128][72];
  const int t = threadIdx.x;
  const int m0 = blockIdx.x * 128, o0 = blockIdx.y * 128;
  const int w = t >> 6, lane = t & 63, quad = lane >> 4, l16 = lane & 15;
  const int wq = w & 1, wj = w >> 1;

  f32x4_t acc[4][4];
#pragma unroll
  for (int a = 0; a < 4; ++a)
#pragma unroll
    for (int c = 0; c < 4; ++c) acc[a][c] = (f32x4_t)0.f;

  const size_t xbase = (size_t)m0 * D_;
  const size_t wbase = (size_t)o0 * D_;

  for (int c0 = 0; c0 < D_; c0 += 64) {
#pragma unroll
    for (int it = 0; it < 4; ++it) {
      const int unit = t + 256 * it;
      const int row = unit >> 3, u = (unit & 7) * 8;
      const size_t go = (size_t)row * D_ + c0 + u;
      *(uint4*)&Xh[row][u] = *(const uint4*)&xh[xbase + go];
      *(uint4*)&Xl[row][u] = *(const uint4*)&xl[xbase + go];
      *(uint4*)&Bh[row][u] = *(const uint4*)&Wh[wbase + go];
      *(uint4*)&Bl[row][u] = *(const uint4*)&Wl[wbase + go];
    }
    __syncthreads();
#pragma unroll
    for (int ks = 0; ks < 2; ++ks) {
      const int dcol = ks * 32 + quad * 8;
      bf16x8_t ah[4], al[4], bh[4], bl[4];
#pragma unroll
      for (int x = 0; x < 4; ++x) {
        ah[x] = *(const bf16x8_t*)&Xh[wq * 64 + x * 16 + l16][dcol];
        al[x] = *(const bf16x8_t*)&Xl[wq * 64 + x * 16 + l16][dcol];
        bh[x] = *(const bf16x8_t*)&Bh[wj * 64 + x * 16 + l16][dcol];
        bl[x] = *(const bf16x8_t*)&Bl[wj * 64 + x * 16 + l16][dcol];
      }
#pragma unroll
      for (int at = 0; at < 4; ++at)
#pragma unroll
        for (int jt = 0; jt < 4; ++jt) {
          acc[at][jt] = __builtin_amdgcn_mfma_f32_16x16x32_bf16(ah[at], bh[jt], acc[at][jt], 0, 0, 0);
          acc[at][jt] = __builtin_amdgcn_mfma_f32_16x16x32_bf16(ah[at], bl[jt], acc[at][jt], 0, 0, 0);
          acc[at][jt] = __builtin_amdgcn_mfma_f32_16x16x32_bf16(al[at], bh[jt], acc[at][jt], 0, 0, 0);
        }
    }
    __syncthreads();
  }
#pragma unroll
  for (int at = 0; at < 4; ++at) {
#pragma unroll
    for (int jt = 0; jt < 4; ++jt) {
      const int o = o0 + wj * 64 + jt * 16 + l16;
      const float bv = bias[o];
#pragma unroll
      for (int r = 0; r < 4; ++r) {
        const int m = m0 + wq * 64 + at * 16 + quad * 4 + r;
        const float v = acc[at][jt][r] + bv;
        const unsigned short hb = f2bf(v);
        yh[(size_t)m * D_ + o] = hb;
        yl[(size_t)m * D_ + o] = f2bf(v - bf2f(hb));
      }
    }
  }
}

// ---------------------------------------------------------------------------
// scores + per-jblock softmax stats: Pb = bf16(exp(s - m_jb)),
// stat[jb][row] = (m_jb, l_jb). K-loop identical to verified scores_mfma.
// ---------------------------------------------------------------------------
__global__ __launch_bounds__(256, 2) void scores_p(const unsigned short* __restrict__ qh,
                                                   const unsigned short* __restrict__ ql,
                                                   const unsigned short* __restrict__ kh,
                                                   const unsigned short* __restrict__ kl,
                                                   unsigned short* __restrict__ Pb,
                                                   float2* __restrict__ stat) {
  __shared__ __align__(16) unsigned short Qh[128][72];
  __shared__ __align__(16) unsigned short Ql[128][72];
  __shared__ __align__(16) unsigned short Kh[128][72];
  __shared__ __align__(16) unsigned short Kl[128][72];
  __shared__ float mred[2][128];
  __shared__ float lred[2][128];
  const int t = threadIdx.x;
  const int b = blockIdx.z;
  const int i0 = blockIdx.x * 128, j0 = blockIdx.y * 128;
  const int jb = blockIdx.y;   // 0..15
  const int w = t >> 6, lane = t & 63, quad = lane >> 4, l16 = lane & 15;
  const int wq = w & 1, wj = w >> 1;

  f32x4_t acc[4][4];
#pragma unroll
  for (int a = 0; a < 4; ++a)
#pragma unroll
    for (int c = 0; c < 4; ++c) acc[a][c] = (f32x4_t)0.f;

  const size_t qbase = ((size_t)b * NQ_ + i0) * D_;
  const size_t kbase = ((size_t)b * NK_ + j0) * D_;

  for (int c0 = 0; c0 < D_; c0 += 64) {
#pragma unroll
    for (int it = 0; it < 4; ++it) {
      const int unit = t + 256 * it;
      const int row = unit >> 3, u = (unit & 7) * 8;
      const size_t go = (size_t)row * D_ + c0 + u;
      *(uint4*)&Qh[row][u] = *(const uint4*)&qh[qbase + go];
      *(uint4*)&Ql[row][u] = *(const uint4*)&ql[qbase + go];
      *(uint4*)&Kh[row][u] = *(const uint4*)&kh[kbase + go];
      *(uint4*)&Kl[row][u] = *(const uint4*)&kl[kbase + go];
    }
    __syncthreads();
#pragma unroll
    for (int ks = 0; ks < 2; ++ks) {
      const int dcol = ks * 32 + quad * 8;
      bf16x8_t ah[4], al[4], bh[4], bl[4];
#pragma unroll
      for (int x = 0; x < 4; ++x) {
        ah[x] = *(const bf16x8_t*)&Qh[wq * 64 + x * 16 + l16][dcol];
        al[x] = *(const bf16x8_t*)&Ql[wq * 64 + x * 16 + l16][dcol];
        bh[x] = *(const bf16x8_t*)&Kh[wj * 64 + x * 16 + l16][dcol];
        bl[x] = *(const bf16x8_t*)&Kl[wj * 64 + x * 16 + l16][dcol];
      }
#pragma unroll
      for (int at = 0; at < 4; ++at)
#pragma unroll
        for (int jt = 0; jt < 4; ++jt) {
          acc[at][jt] = __builtin_amdgcn_mfma_f32_16x16x32_bf16(ah[at], bh[jt], acc[at][jt], 0, 0, 0);
          acc[at][jt] = __builtin_amdgcn_mfma_f32_16x16x32_bf16(ah[at], bl[jt], acc[at][jt], 0, 0, 0);
          acc[at][jt] = __builtin_amdgcn_mfma_f32_16x16x32_bf16(al[at], bh[jt], acc[at][jt], 0, 0, 0);
        }
    }
    __syncthreads();
  }

  // --- epilogue: per-row (over this block's 128 j) max, exp, sum, bf16 store
  const float scale = 0.0625f;
  float mt[4][4];
#pragma unroll
  for (int at = 0; at < 4; ++at)
#pragma unroll
    for (int r = 0; r < 4; ++r) mt[at][r] = -3e38f;
#pragma unroll
  for (int at = 0; at < 4; ++at)
#pragma unroll
    for (int jt = 0; jt < 4; ++jt)
#pragma unroll
      for (int r = 0; r < 4; ++r) {
        acc[at][jt][r] *= scale;
        mt[at][r] = fmaxf(mt[at][r], acc[at][jt][r]);
      }
#pragma unroll
  for (int off = 1; off < 16; off <<= 1)
#pragma unroll
    for (int at = 0; at < 4; ++at)
#pragma unroll
      for (int r = 0; r < 4; ++r) mt[at][r] = fmaxf(mt[at][r], __shfl_xor(mt[at][r], off));
  if (l16 == 0) {
#pragma unroll
    for (int at = 0; at < 4; ++at)
#pragma unroll
      for (int r = 0; r < 4; ++r)
        mred[wj][wq * 64 + at * 16 + quad * 4 + r] = mt[at][r];
  }
  __syncthreads();
  float mrow[4][4], lt[4][4];
#pragma unroll
  for (int at = 0; at < 4; ++at)
#pragma unroll
    for (int r = 0; r < 4; ++r) {
      const int rr = wq * 64 + at * 16 + quad * 4 + r;
      mrow[at][r] = fmaxf(mred[0][rr], mred[1][rr]);
      lt[at][r] = 0.f;
    }
#pragma unroll
  for (int at = 0; at < 4; ++at)
#pragma unroll
    for (int jt = 0; jt < 4; ++jt) {
      const int j = j0 + wj * 64 + jt * 16 + l16;
#pragma unroll
      for (int r = 0; r < 4; ++r) {
        const int i = i0 + wq * 64 + at * 16 + quad * 4 + r;
        const float p = __expf(acc[at][jt][r] - mrow[at][r]);
        lt[at][r] += p;
        Pb[((size_t)b * NQ_ + i) * NK_ + j] = f2bf(p);
      }
    }
#pragma unroll
  for (int off = 1; off < 16; off <<= 1)
#pragma unroll
    for (int at = 0; at < 4; ++at)
#pragma unroll
      for (int r = 0; r < 4; ++r) lt[at][r] += __shfl_xor(lt[at][r], off);
  if (l16 == 0) {
#pragma unroll
    for (int at = 0; at < 4; ++at)
#pragma unroll
      for (int r = 0; r < 4; ++r)
        lred[wj][wq * 64 + at * 16 + quad * 4 + r] = lt[at][r];
  }
  __syncthreads();
  if (wj == 0 && l16 == 0) {
#pragma unroll
    for (int at = 0; at < 4; ++at)
#pragma unroll
      for (int r = 0; r < 4; ++r) {
        const int rr = wq * 64 + at * 16 + quad * 4 + r;
        stat[(size_t)jb * (B_ * NQ_) + (size_t)b * NQ_ + i0 + rr] =
            make_float2(mrow[at][r], lred[0][rr] + lred[1][rr]);
      }
  }
}

// ---------------------------------------------------------------------------
// per-row global stats from 16 jblock stats: srow = (m, 1/l)
// ---------------------------------------------------------------------------
__global__ __launch_bounds__(256) void rowfin_kernel(const float2* __restrict__ stat,
                                                     float2* __restrict__ srow) {
  const int i = blockIdx.x * 256 + threadIdx.x;   // 0..16383
  float2 st[16];
  float m = -3e38f;
#pragma unroll
  for (int jb = 0; jb < 16; ++jb) {
    st[jb] = stat[(size_t)jb * (B_ * NQ_) + i];
    m = fmaxf(m, st[jb].x);
  }
  float l = 0.f;
#pragma unroll
  for (int jb = 0; jb < 16; ++jb) l += st[jb].y * __expf(st[jb].x - m);
  srow[i] = make_float2(m, 1.0f / l);
}

// ---------------------------------------------------------------------------
// out[m,d] += sum_{j in split} (Pb[m,j]*e^{m_jb-m}/l) * V[j,d]
// Block: 128 rows x 256 d, 4 waves. j-split=4 (512 each). bf16 P staging.
// ---------------------------------------------------------------------------
__global__ __launch_bounds__(256, 2) void pv_p(const unsigned short* __restrict__ Pb,
                                               const float2* __restrict__ stat,
                                               const float2* __restrict__ srow,
                                               const unsigned short* __restrict__ Vt,
                                               float* __restrict__ out) {
  __shared__ __align__(16) unsigned short Ps[128][72];
  __shared__ __align__(16) unsigned short Vs[256][72];
  const int t = threadIdx.x;
  const int m0 = blockIdx.x * 128;
  const int b  = blockIdx.x >> 4;
  const int j0 = blockIdx.y * 512;
  const int w = t >> 6, lane = t & 63, quad = lane >> 4, l16 = lane & 15;
  const int wq = w & 1, wd = w >> 1;

  f32x4_t acc[4][8];
#pragma unroll
  for (int a = 0; a < 4; ++a)
#pragma unroll
    for (int c = 0; c < 8; ++c) acc[a][c] = (f32x4_t)0.f;

  for (int jc = 0; jc < 512; jc += 64) {
    const int jb = (j0 + jc) >> 7;
    // stage P tile: bf16 load, scale by f = e^{m_jb-m}/l, bf16 store
#pragma unroll
    for (int it = 0; it < 4; ++it) {
      const int unit = t + 256 * it;
      const int row = unit >> 3, u = (unit & 7) * 8;
      const float2 sr = srow[m0 + row];
      const float f = __expf(stat[(size_t)jb * (B_ * NQ_) + m0 + row].x - sr.x) * sr.y;
      const uint4 pk = *(const uint4*)&Pb[((size_t)(m0 + row)) * NK_ + j0 + jc + u];
      uint4 outp;
      {
        const unsigned int a0 = pk.x, a1 = pk.y, a2 = pk.z, a3 = pk.w;
        const float v0 = bf2f((unsigned short)(a0 & 0xFFFF)) * f;
        const float v1 = bf2f((unsigned short)(a0 >> 16)) * f;
        const float v2 = bf2f((unsigned short)(a1 & 0xFFFF)) * f;
        const float v3 = bf2f((unsigned short)(a1 >> 16)) * f;
        const float v4 = bf2f((unsigned short)(a2 & 0xFFFF)) * f;
        const float v5 = bf2f((unsigned short)(a2 >> 16)) * f;
        const float v6 = bf2f((unsigned short)(a3 & 0xFFFF)) * f;
        const float v7 = bf2f((unsigned short)(a3 >> 16)) * f;
        outp.x = (unsigned int)f2bf(v0) | ((unsigned int)f2bf(v1) << 16);
        outp.y = (unsigned int)f2bf(v2) | ((unsigned int)f2bf(v3) << 16);
        outp.z = (unsigned int)f2bf(v4) | ((unsigned int)f2bf(v5) << 16);
        outp.w = (unsigned int)f2bf(v6) | ((unsigned int)f2bf(v7) << 16);
      }
      *(uint4*)&Ps[row][u] = outp;
    }
    // stage Vt tile: 256 d-rows x 64 j
#pragma unroll
    for (int it = 0; it < 8; ++it) {
      const int unit = t + 256 * it;
      const int row = unit >> 3, u = (unit & 7) * 8;
      *(uint4*)&Vs[row][u] = *(const uint4*)&Vt[((size_t)b * D_ + row) * NK_ + j0 + jc + u];
    }
    __syncthreads();
#pragma unroll
    for (int ks = 0; ks < 2; ++ks) {
      const int jcol = ks * 32 + quad * 8;
      bf16x8_t a[4], bv[8];
#pragma unroll
      for (int x = 0; x < 4; ++x)
        a[x] = *(const bf16x8_t*)&Ps[wq * 64 + x * 16 + l16][jcol];
#pragma unroll
      for (int y = 0; y < 8; ++y)
        bv[y] = *(const bf16x8_t*)&Vs[wd * 128 + y * 16 + l16][jcol];
#pragma unroll
      for (int at = 0; at < 4; ++at)
#pragma unroll
        for (int bt = 0; bt < 8; ++bt)
          acc[at][bt] = __builtin_amdgcn_mfma_f32_16x16x32_bf16(a[at], bv[bt], acc[at][bt], 0, 0, 0);
    }
    __syncthreads();
  }
#pragma unroll
  for (int at = 0; at < 4; ++at) {
#pragma unroll
    for (int bt = 0; bt < 8; ++bt) {
      const int d = wd * 128 + bt * 16 + l16;
#pragma unroll
      for (int r = 0; r < 4; ++r) {
        const int m = m0 + wq * 64 + at * 16 + quad * 4 + r;
        atomicAdd(&out[(size_t)m * D_ + d], acc[at][bt][r]);
      }
    }
  }
}

extern "C" void kernel_launch(void* const* d_in, const int* in_sizes, int n_in,
                              void* d_out, int out_size, void* d_ws, size_t ws_size,
                              hipStream_t stream) {
  const float* query = (const float*)d_in[0];
  const float* key   = (const float*)d_in[1];
  const float* Wq    = (const float*)d_in[2];
  const float* bq    = (const float*)d_in[3];
  const float* Wk    = (const float*)d_in[4];
  const float* bk    = (const float*)d_in[5];
  float* out = (float*)d_out;

  char* ws = (char*)d_ws;
  const size_t MB = (size_t)1 << 20;
  // persistent:
  unsigned short* qh = (unsigned short*)(ws);             // 8 MB
  unsigned short* ql = (unsigned short*)(ws + 8 * MB);
  unsigned short* kh = (unsigned short*)(ws + 16 * MB);
  unsigned short* kl = (unsigned short*)(ws + 24 * MB);
  unsigned short* Vt = (unsigned short*)(ws + 32 * MB);
  unsigned short* Pb = (unsigned short*)(ws + 40 * MB);   // 64 MB (bf16 16384x2048)
  float2* stat = (float2*)(ws + 108 * MB);                // 2 MB (16 x 16384 x 8B)
  float2* srow = (float2*)(ws + 110 * MB);                // 128 KB
  // transients overlaid on the Pb region (all dead before scores_p writes Pb):
  unsigned short* Ch   = (unsigned short*)(ws + 40 * MB);   // 4.5 MB
  unsigned short* Cl   = (unsigned short*)(ws + 45 * MB);   // 4.5 MB
  unsigned short* Qth  = (unsigned short*)(ws + 50 * MB);   // 8 MB
  unsigned short* Qtl  = (unsigned short*)(ws + 58 * MB);   // 8 MB
  float*          qr   = (float*)(ws + 66 * MB);            // 9.44 MB
  unsigned short* qrh  = (unsigned short*)(ws + 76 * MB);   // 8 MB
  unsigned short* qrl  = (unsigned short*)(ws + 84 * MB);   // 8 MB
  unsigned short* keyh = (unsigned short*)(ws + 92 * MB);   // 8 MB
  unsigned short* keyl = (unsigned short*)(ws + 100 * MB);  // 8 MB
  unsigned short* Wqh  = (unsigned short*)(ws + 111 * MB);  // 128 KB
  unsigned short* Wql  = (unsigned short*)(ws + 111 * MB + 256 * 1024);
  unsigned short* Wkh  = (unsigned short*)(ws + 111 * MB + 512 * 1024);
  unsigned short* Wkl  = (unsigned short*)(ws + 111 * MB + 768 * 1024);

  dim3 blk(256);
  hipMemsetAsync(qr, 0, (size_t)B_ * 1152 * D_ * sizeof(float), stream);
  hipMemsetAsync(out, 0, (size_t)B_ * NQ_ * D_ * sizeof(float), stream);

  split_kernel<<<B_ * NK_ * D_ / 256, blk, 0, stream>>>(key, keyh, keyl, B_ * NK_ * D_);
  split_kernel<<<D_ * D_ / 256, blk, 0, stream>>>(Wq, Wqh, Wql, D_ * D_);
  split_kernel<<<D_ * D_ / 256, blk, 0, stream>>>(Wk, Wkh, Wkl, D_ * D_);
  cos_split_kernel<<<1152 * 2048 / 256, blk, 0, stream>>>(Ch, Cl);
  qt_split_kernel<<<dim3(NQ_ / 32, D_ / 32, B_), blk, 0, stream>>>(query, Qth, Qtl);
  // DFT
  dft_mfma<<<dim3(9, 2, B_ * 4), blk, 0, stream>>>(Ch, Cl, Qth, Qtl, qr);
  qr_finalize_kernel<<<dim3(2048, B_), blk, 0, stream>>>(qr, qrh, qrl);
  // projections
  proj_mfma<<<dim3(B_ * NQ_ / 128, 2), blk, 0, stream>>>(qrh, qrl, Wqh, Wql, bq, qh, ql);
  proj_mfma<<<dim3(B_ * NK_ / 128, 2), blk, 0, stream>>>(keyh, keyl, Wkh, Wkl, bk, kh, kl);
  vt_bf16_kernel<<<dim3(NK_ / 32, D_ / 32, B_), blk, 0, stream>>>(keyh, Vt);
  // attention: scores (bf16 P + per-jb stats) -> per-row stats -> PV
  scores_p<<<dim3(NQ_ / 128, NK_ / 128, B_), blk, 0, stream>>>(qh, ql, kh, kl, Pb, stat);
  rowfin_kernel<<<B_ * NQ_ / 256, blk, 0, stream>>>(stat, srow);
  pv_p<<<dim3(B_ * NQ_ / 128, 4), blk, 0, stream>>>(Pb, stat, srow, Vt, out);
}